// Round 1
// baseline (157.081 us; speedup 1.0000x reference)
//
#include <hip/hip_runtime.h>

#define QD 512
#define SD 64
#define NCTX 32

constexpr float EPS_LN = 1e-6f;
constexpr float SLOPE = 0.01f;

__device__ __forceinline__ float red64(float v) {
#pragma unroll
    for (int m = 32; m; m >>= 1) v += __shfl_xor(v, m, 64);
    return v;
}

// ---------------------------------------------------------------------------
// Kernel A: per-batch fused attention + sigmoid + residual + pre-LayerNorm.
// One block (256 thr) per batch element. key[b] staged in LDS (64 KB) so
// key_embeds is fetched from HBM exactly once.
// ---------------------------------------------------------------------------
__global__ __launch_bounds__(256) void attn_fuse(
    const float* __restrict__ key, const float* __restrict__ spa,
    const float* __restrict__ query, const float* __restrict__ av,
    const float* __restrict__ lng, const float* __restrict__ lnb,
    float* __restrict__ yout)
{
    __shared__ float s_key[NCTX * QD];   // 64 KB
    __shared__ float s_q[QD];            // 2 KB
    __shared__ float s_logit[NCTX][4];
    __shared__ float s_w[NCTX];
    __shared__ float s_red[8];

    const int b = blockIdx.x;
    const int t = threadIdx.x;
    const int wave = t >> 6;
    const int lane = t & 63;

    const float* kb = key + (size_t)b * (NCTX * QD);

    // ---- stage key tile + q into LDS (coalesced float4) ----
#pragma unroll
    for (int i = 0; i < 16; ++i) {
        const int idx = t + 256 * i;
        const float4 v = reinterpret_cast<const float4*>(kb)[idx];
        reinterpret_cast<float4*>(s_key)[idx] = v;
    }
    if (t < QD / 4) {
        reinterpret_cast<float4*>(s_q)[t] =
            reinterpret_cast<const float4*>(query + (size_t)b * QD)[t];
    }
    __syncthreads();

    // ---- logits: attn[n][k] = leaky( q.avq[k] + key[n].avk[k] + spa[n].avs[k] )
    // preload atten_vecs key/spa slices for this lane (registers, L1-hot)
    float4 avk[8];
#pragma unroll
    for (int jj = 0; jj < 2; ++jj)
#pragma unroll
        for (int e = 0; e < 4; ++e)
            avk[jj * 4 + e] =
                reinterpret_cast<const float4*>(av)[QD + jj * 256 + 4 * lane + e];
    const float4 avs = reinterpret_cast<const float4*>(av)[2 * QD + lane];

    // query logit: n-independent, computed once per wave (redundant x4)
    float ql0 = 0.f, ql1 = 0.f, ql2 = 0.f, ql3 = 0.f;
#pragma unroll
    for (int j = 0; j < 8; ++j) {
        const int d = j * 64 + lane;
        const float qv = s_q[d];
        const float4 a = reinterpret_cast<const float4*>(av)[d];
        ql0 += qv * a.x; ql1 += qv * a.y; ql2 += qv * a.z; ql3 += qv * a.w;
    }
    ql0 = red64(ql0); ql1 = red64(ql1); ql2 = red64(ql2); ql3 = red64(ql3);

    const float* sb = spa + (size_t)b * (NCTX * SD);
#pragma unroll
    for (int i = 0; i < 8; ++i) {
        const int n = wave * 8 + i;           // each wave owns 8 context points
        float p0 = 0.f, p1 = 0.f, p2 = 0.f, p3 = 0.f;
#pragma unroll
        for (int jj = 0; jj < 2; ++jj) {
            const float4 kv = *reinterpret_cast<const float4*>(
                &s_key[n * QD + jj * 256 + 4 * lane]);
            const float4 a0 = avk[jj * 4 + 0], a1 = avk[jj * 4 + 1],
                         a2 = avk[jj * 4 + 2], a3 = avk[jj * 4 + 3];
            p0 += kv.x * a0.x + kv.y * a1.x + kv.z * a2.x + kv.w * a3.x;
            p1 += kv.x * a0.y + kv.y * a1.y + kv.z * a2.y + kv.w * a3.y;
            p2 += kv.x * a0.z + kv.y * a1.z + kv.z * a2.z + kv.w * a3.z;
            p3 += kv.x * a0.w + kv.y * a1.w + kv.z * a2.w + kv.w * a3.w;
        }
        const float sv = sb[n * SD + lane];   // SD==64: one elem per lane
        p0 += sv * avs.x; p1 += sv * avs.y; p2 += sv * avs.z; p3 += sv * avs.w;
        p0 = red64(p0); p1 = red64(p1); p2 = red64(p2); p3 = red64(p3);
        if (lane == 0) {
            float l0 = ql0 + p0, l1 = ql1 + p1, l2 = ql2 + p2, l3 = ql3 + p3;
            l0 = l0 > 0.f ? l0 : SLOPE * l0;
            l1 = l1 > 0.f ? l1 : SLOPE * l1;
            l2 = l2 > 0.f ? l2 : SLOPE * l2;
            l3 = l3 > 0.f ? l3 : SLOPE * l3;
            s_logit[n][0] = l0; s_logit[n][1] = l1;
            s_logit[n][2] = l2; s_logit[n][3] = l3;
        }
    }
    __syncthreads();

    // ---- softmax over n per head, then w[n] = 0.25 * sum_k attn[n][k] ----
    if (wave == 0) {
        const int n = lane & 31;              // duplicated in both halves
        float v0 = s_logit[n][0], v1 = s_logit[n][1],
              v2 = s_logit[n][2], v3 = s_logit[n][3];
        float m0 = v0, m1 = v1, m2 = v2, m3 = v3;
#pragma unroll
        for (int m = 16; m; m >>= 1) {
            m0 = fmaxf(m0, __shfl_xor(m0, m, 32));
            m1 = fmaxf(m1, __shfl_xor(m1, m, 32));
            m2 = fmaxf(m2, __shfl_xor(m2, m, 32));
            m3 = fmaxf(m3, __shfl_xor(m3, m, 32));
        }
        float e0 = __expf(v0 - m0), e1 = __expf(v1 - m1),
              e2 = __expf(v2 - m2), e3 = __expf(v3 - m3);
        float st0 = e0, st1 = e1, st2 = e2, st3 = e3;
#pragma unroll
        for (int m = 16; m; m >>= 1) {
            st0 += __shfl_xor(st0, m, 32);
            st1 += __shfl_xor(st1, m, 32);
            st2 += __shfl_xor(st2, m, 32);
            st3 += __shfl_xor(st3, m, 32);
        }
        const float w = 0.25f * (e0 / st0 + e1 / st1 + e2 / st2 + e3 / st3);
        if (lane < 32) s_w[n] = w;
    }
    __syncthreads();

    // ---- weighted sum over n, sigmoid, +query residual, pre-LN ----
    const int d0 = 2 * t;
    float acc0 = 0.f, acc1 = 0.f;
#pragma unroll
    for (int n = 0; n < NCTX; ++n) {
        const float wn = s_w[n];              // LDS broadcast
        const float2 kv = *reinterpret_cast<const float2*>(&s_key[n * QD + d0]);
        acc0 += wn * kv.x; acc1 += wn * kv.y;
    }
    const float x0 = 1.f / (1.f + __expf(-acc0)) + s_q[d0];
    const float x1 = 1.f / (1.f + __expf(-acc1)) + s_q[d0 + 1];

    float sum = red64(x0 + x1);
    float ssq = red64(x0 * x0 + x1 * x1);
    if (lane == 0) { s_red[wave] = sum; s_red[4 + wave] = ssq; }
    __syncthreads();
    sum = s_red[0] + s_red[1] + s_red[2] + s_red[3];
    ssq = s_red[4] + s_red[5] + s_red[6] + s_red[7];
    const float mean = sum * (1.f / QD);
    const float var = ssq * (1.f / QD) - mean * mean;
    const float inv = rsqrtf(var + EPS_LN);
    const float2 gg = *reinterpret_cast<const float2*>(&lng[d0]);
    const float2 bb = *reinterpret_cast<const float2*>(&lnb[d0]);
    float2 o;
    o.x = gg.x * (x0 - mean) * inv + bb.x;
    o.y = gg.y * (x1 - mean) * inv + bb.y;
    *reinterpret_cast<float2*>(&yout[(size_t)b * QD + d0]) = o;
}

// ---------------------------------------------------------------------------
// Kernel B: lin = Y @ W^T + bias.  64x64 tiles, 4x4 micro-tiles, K-chunk 16.
// LDS row stride 68 keeps aliasing <= 2-way (free).
// ---------------------------------------------------------------------------
__global__ __launch_bounds__(256) void post_gemm(
    const float* __restrict__ Y, const float* __restrict__ W,
    const float* __restrict__ pbias, float* __restrict__ out)
{
    __shared__ float Ys[16][68];
    __shared__ float Ws[16][68];
    const int t = threadIdx.x;
    const int bm = blockIdx.x * 64;
    const int bn = blockIdx.y * 64;
    const int tx = t & 15, ty = t >> 4;
    const int lm = t >> 2;          // 0..63: tile row being loaded
    const int lk = (t & 3) * 4;     // k offset within chunk

    float acc[4][4] = {};

    for (int kc = 0; kc < QD; kc += 16) {
        const float4 yv = *reinterpret_cast<const float4*>(
            &Y[(size_t)(bm + lm) * QD + kc + lk]);
        const float4 wv = *reinterpret_cast<const float4*>(
            &W[(size_t)(bn + lm) * QD + kc + lk]);
        __syncthreads();   // previous chunk's reads done before overwrite
        Ys[lk + 0][lm] = yv.x; Ys[lk + 1][lm] = yv.y;
        Ys[lk + 2][lm] = yv.z; Ys[lk + 3][lm] = yv.w;
        Ws[lk + 0][lm] = wv.x; Ws[lk + 1][lm] = wv.y;
        Ws[lk + 2][lm] = wv.z; Ws[lk + 3][lm] = wv.w;
        __syncthreads();
#pragma unroll
        for (int k = 0; k < 16; ++k) {
            const float4 a = *reinterpret_cast<const float4*>(&Ys[k][ty * 4]);
            const float4 bv = *reinterpret_cast<const float4*>(&Ws[k][tx * 4]);
            acc[0][0] += a.x * bv.x; acc[0][1] += a.x * bv.y; acc[0][2] += a.x * bv.z; acc[0][3] += a.x * bv.w;
            acc[1][0] += a.y * bv.x; acc[1][1] += a.y * bv.y; acc[1][2] += a.y * bv.z; acc[1][3] += a.y * bv.w;
            acc[2][0] += a.z * bv.x; acc[2][1] += a.z * bv.y; acc[2][2] += a.z * bv.z; acc[2][3] += a.z * bv.w;
            acc[3][0] += a.w * bv.x; acc[3][1] += a.w * bv.y; acc[3][2] += a.w * bv.z; acc[3][3] += a.w * bv.w;
        }
    }
    const float4 pb4 = *reinterpret_cast<const float4*>(&pbias[bn + tx * 4]);
#pragma unroll
    for (int i = 0; i < 4; ++i) {
        float4 o;
        o.x = acc[i][0] + pb4.x;
        o.y = acc[i][1] + pb4.y;
        o.z = acc[i][2] + pb4.z;
        o.w = acc[i][3] + pb4.w;
        *reinterpret_cast<float4*>(
            &out[(size_t)(bm + ty * 4 + i) * QD + bn + tx * 4]) = o;
    }
}

// ---------------------------------------------------------------------------
// Kernel C: out = LN(lin + y), in-place on d_out (block owns full row).
// ---------------------------------------------------------------------------
__global__ __launch_bounds__(256) void post_ln_kernel(
    float* __restrict__ out, const float* __restrict__ yres,
    const float* __restrict__ lng, const float* __restrict__ lnb)
{
    __shared__ float s_red[8];
    const int r = blockIdx.x;
    const int t = threadIdx.x;
    const int wave = t >> 6, lane = t & 63;
    const int d0 = 2 * t;
    const float2 lv = *reinterpret_cast<const float2*>(&out[(size_t)r * QD + d0]);
    const float2 yv = *reinterpret_cast<const float2*>(&yres[(size_t)r * QD + d0]);
    const float x0 = lv.x + yv.x;
    const float x1 = lv.y + yv.y;
    float sum = red64(x0 + x1);
    float ssq = red64(x0 * x0 + x1 * x1);
    if (lane == 0) { s_red[wave] = sum; s_red[4 + wave] = ssq; }
    __syncthreads();
    sum = s_red[0] + s_red[1] + s_red[2] + s_red[3];
    ssq = s_red[4] + s_red[5] + s_red[6] + s_red[7];
    const float mean = sum * (1.f / QD);
    const float var = ssq * (1.f / QD) - mean * mean;
    const float inv = rsqrtf(var + EPS_LN);
    const float2 gg = *reinterpret_cast<const float2*>(&lng[d0]);
    const float2 bb = *reinterpret_cast<const float2*>(&lnb[d0]);
    float2 o;
    o.x = gg.x * (x0 - mean) * inv + bb.x;
    o.y = gg.y * (x1 - mean) * inv + bb.y;
    *reinterpret_cast<float2*>(&out[(size_t)r * QD + d0]) = o;
}

// ---------------------------------------------------------------------------
extern "C" void kernel_launch(void* const* d_in, const int* in_sizes, int n_in,
                              void* d_out, int out_size, void* d_ws, size_t ws_size,
                              hipStream_t stream) {
    const float* key    = (const float*)d_in[0];   // [B,32,512]
    const float* spa    = (const float*)d_in[1];   // [B,32,64]
    const float* query  = (const float*)d_in[2];   // [B,512]
    const float* av     = (const float*)d_in[3];   // [1088,4]
    const float* postw  = (const float*)d_in[4];   // [512,512]
    const float* postb  = (const float*)d_in[5];   // [512]
    const float* pre_g  = (const float*)d_in[6];
    const float* pre_b  = (const float*)d_in[7];
    const float* post_g = (const float*)d_in[8];
    const float* post_b = (const float*)d_in[9];
    float* out = (float*)d_out;
    float* yws = (float*)d_ws;                     // y (pre-LN'd combined), 8 MB

    const int B = in_sizes[2] / QD;                // 4096

    attn_fuse<<<B, 256, 0, stream>>>(key, spa, query, av, pre_g, pre_b, yws);
    dim3 gridB(B / 64, QD / 64);
    post_gemm<<<gridB, 256, 0, stream>>>(yws, postw, postb, out);
    post_ln_kernel<<<B, 256, 0, stream>>>(out, yws, post_g, post_b);
}

// Round 4
// 129.691 us; speedup vs baseline: 1.2112x; 1.2112x over previous
//
#include <hip/hip_runtime.h>
#include <hip/hip_bf16.h>

#define QD 512
#define SD 64
#define NCTX 32

constexpr float EPS_LN = 1e-6f;
constexpr float SLOPE = 0.01f;

__device__ __forceinline__ float red64(float v) {
#pragma unroll
    for (int m = 32; m; m >>= 1) v += __shfl_xor(v, m, 64);
    return v;
}

__device__ __forceinline__ float b2f(unsigned short u) {
    unsigned int x = ((unsigned int)u) << 16;
    return __builtin_bit_cast(float, x);
}
__device__ __forceinline__ unsigned short f2b(float f) {
    __hip_bfloat16 h = __float2bfloat16(f);
    return __builtin_bit_cast(unsigned short, h);
}

struct __align__(16) US8 { ushort4 a, b; };

// ---------------------------------------------------------------------------
// Kernel A: per-batch fused attention + sigmoid + residual + pre-LayerNorm.
// One block (256 thr) per batch element. key[b] staged in LDS as bf16 (32 KB)
// so key_embeds is fetched from HBM exactly once AND 4 blocks/CU stay
// resident (16 waves/CU) for load/compute overlap across blocks.
// ---------------------------------------------------------------------------
__global__ __launch_bounds__(256, 4) void attn_fuse(
    const float* __restrict__ key, const float* __restrict__ spa,
    const float* __restrict__ query, const float* __restrict__ av,
    const float* __restrict__ lng, const float* __restrict__ lnb,
    float* __restrict__ yout)
{
    __shared__ __align__(16) unsigned short s_key[NCTX * QD];  // 32 KB bf16
    __shared__ float s_q[QD];                                  // 2 KB
    __shared__ float s_logit[NCTX][4];
    __shared__ float s_w[NCTX];
    __shared__ float s_red[8];

    const int b = blockIdx.x;
    const int t = threadIdx.x;
    const int wave = t >> 6;
    const int lane = t & 63;

    const float* kb = key + (size_t)b * (NCTX * QD);
    const float4* av4 = reinterpret_cast<const float4*>(av);   // row d -> 4 heads

    // ---- stage key tile (f32 -> bf16) + q into LDS, coalesced float4 ----
#pragma unroll
    for (int i = 0; i < 16; ++i) {
        const int idx = t + 256 * i;                           // float4 index
        const float4 v = reinterpret_cast<const float4*>(kb)[idx];
        ushort4 h;
        h.x = f2b(v.x); h.y = f2b(v.y); h.z = f2b(v.z); h.w = f2b(v.w);
        reinterpret_cast<ushort4*>(s_key)[idx] = h;
    }
    if (t < QD / 4) {
        reinterpret_cast<float4*>(s_q)[t] =
            reinterpret_cast<const float4*>(query + (size_t)b * QD)[t];
    }
    __syncthreads();

    // ---- per-lane av slices: lane owns d in [8*lane, 8*lane+8) for key ----
    float4 avk[8];
#pragma unroll
    for (int e = 0; e < 8; ++e) avk[e] = av4[QD + 8 * lane + e];
    const float4 avs = av4[2 * QD + lane];                     // spa row (SD==64)

    // ---- query logit (n-independent), strided mapping (conflict-free) ----
    float ql0 = 0.f, ql1 = 0.f, ql2 = 0.f, ql3 = 0.f;
#pragma unroll
    for (int j = 0; j < 8; ++j) {
        const int d = j * 64 + lane;
        const float qv = s_q[d];
        const float4 a = av4[d];
        ql0 += qv * a.x; ql1 += qv * a.y; ql2 += qv * a.z; ql3 += qv * a.w;
    }
    ql0 = red64(ql0); ql1 = red64(ql1); ql2 = red64(ql2); ql3 = red64(ql3);

    // ---- key/spa logits: each wave owns 8 context points ----
    const float* sb = spa + (size_t)b * (NCTX * SD);
#pragma unroll
    for (int i = 0; i < 8; ++i) {
        const int n = wave * 8 + i;
        const US8 kv = *reinterpret_cast<const US8*>(&s_key[n * QD + 8 * lane]);
        float p0 = 0.f, p1 = 0.f, p2 = 0.f, p3 = 0.f;
        float kf;
        kf = b2f(kv.a.x); p0 += kf * avk[0].x; p1 += kf * avk[0].y; p2 += kf * avk[0].z; p3 += kf * avk[0].w;
        kf = b2f(kv.a.y); p0 += kf * avk[1].x; p1 += kf * avk[1].y; p2 += kf * avk[1].z; p3 += kf * avk[1].w;
        kf = b2f(kv.a.z); p0 += kf * avk[2].x; p1 += kf * avk[2].y; p2 += kf * avk[2].z; p3 += kf * avk[2].w;
        kf = b2f(kv.a.w); p0 += kf * avk[3].x; p1 += kf * avk[3].y; p2 += kf * avk[3].z; p3 += kf * avk[3].w;
        kf = b2f(kv.b.x); p0 += kf * avk[4].x; p1 += kf * avk[4].y; p2 += kf * avk[4].z; p3 += kf * avk[4].w;
        kf = b2f(kv.b.y); p0 += kf * avk[5].x; p1 += kf * avk[5].y; p2 += kf * avk[5].z; p3 += kf * avk[5].w;
        kf = b2f(kv.b.z); p0 += kf * avk[6].x; p1 += kf * avk[6].y; p2 += kf * avk[6].z; p3 += kf * avk[6].w;
        kf = b2f(kv.b.w); p0 += kf * avk[7].x; p1 += kf * avk[7].y; p2 += kf * avk[7].z; p3 += kf * avk[7].w;
        const float sv = sb[n * SD + lane];                    // SD==64
        p0 += sv * avs.x; p1 += sv * avs.y; p2 += sv * avs.z; p3 += sv * avs.w;
        p0 = red64(p0); p1 = red64(p1); p2 = red64(p2); p3 = red64(p3);
        if (lane == 0) {
            float l0 = ql0 + p0, l1 = ql1 + p1, l2 = ql2 + p2, l3 = ql3 + p3;
            l0 = l0 > 0.f ? l0 : SLOPE * l0;
            l1 = l1 > 0.f ? l1 : SLOPE * l1;
            l2 = l2 > 0.f ? l2 : SLOPE * l2;
            l3 = l3 > 0.f ? l3 : SLOPE * l3;
            s_logit[n][0] = l0; s_logit[n][1] = l1;
            s_logit[n][2] = l2; s_logit[n][3] = l3;
        }
    }
    __syncthreads();

    // ---- softmax over n per head, w[n] = 0.25 * sum_k attn[n][k] ----
    if (wave == 0) {
        const int n = lane & 31;
        float v0 = s_logit[n][0], v1 = s_logit[n][1],
              v2 = s_logit[n][2], v3 = s_logit[n][3];
        float m0 = v0, m1 = v1, m2 = v2, m3 = v3;
#pragma unroll
        for (int m = 16; m; m >>= 1) {
            m0 = fmaxf(m0, __shfl_xor(m0, m, 32));
            m1 = fmaxf(m1, __shfl_xor(m1, m, 32));
            m2 = fmaxf(m2, __shfl_xor(m2, m, 32));
            m3 = fmaxf(m3, __shfl_xor(m3, m, 32));
        }
        float e0 = __expf(v0 - m0), e1 = __expf(v1 - m1),
              e2 = __expf(v2 - m2), e3 = __expf(v3 - m3);
        float st0 = e0, st1 = e1, st2 = e2, st3 = e3;
#pragma unroll
        for (int m = 16; m; m >>= 1) {
            st0 += __shfl_xor(st0, m, 32);
            st1 += __shfl_xor(st1, m, 32);
            st2 += __shfl_xor(st2, m, 32);
            st3 += __shfl_xor(st3, m, 32);
        }
        const float w = 0.25f * (e0 / st0 + e1 / st1 + e2 / st2 + e3 / st3);
        if (lane < 32) s_w[n] = w;
    }
    __syncthreads();

    // ---- weighted sum over n, sigmoid, +query residual, pre-LN ----
    const int d0 = 2 * t;
    float acc0 = 0.f, acc1 = 0.f;
#pragma unroll
    for (int n = 0; n < NCTX; ++n) {
        const float wn = s_w[n];
        const unsigned int u =
            *reinterpret_cast<const unsigned int*>(&s_key[n * QD + d0]);
        acc0 += wn * b2f((unsigned short)(u & 0xffffu));
        acc1 += wn * b2f((unsigned short)(u >> 16));
    }
    const float x0 = 1.f / (1.f + __expf(-acc0)) + s_q[d0];
    const float x1 = 1.f / (1.f + __expf(-acc1)) + s_q[d0 + 1];

    float sum = red64(x0 + x1);
    float ssq = red64(x0 * x0 + x1 * x1);
    if (lane == 0) { s_red[wave] = sum; s_red[4 + wave] = ssq; }
    __syncthreads();
    sum = s_red[0] + s_red[1] + s_red[2] + s_red[3];
    ssq = s_red[4] + s_red[5] + s_red[6] + s_red[7];
    const float mean = sum * (1.f / QD);
    const float var = ssq * (1.f / QD) - mean * mean;
    const float inv = rsqrtf(var + EPS_LN);
    const float2 gg = *reinterpret_cast<const float2*>(&lng[d0]);
    const float2 bb = *reinterpret_cast<const float2*>(&lnb[d0]);
    float2 o;
    o.x = gg.x * (x0 - mean) * inv + bb.x;
    o.y = gg.y * (x1 - mean) * inv + bb.y;
    *reinterpret_cast<float2*>(&yout[(size_t)b * QD + d0]) = o;
}

// ---------------------------------------------------------------------------
// Kernel B: lin = Y @ W^T + bias.  64x64 tiles, 4x4 micro-tiles, K-chunk 16.
// ---------------------------------------------------------------------------
__global__ __launch_bounds__(256) void post_gemm(
    const float* __restrict__ Y, const float* __restrict__ W,
    const float* __restrict__ pbias, float* __restrict__ out)
{
    __shared__ float Ys[16][68];
    __shared__ float Ws[16][68];
    const int t = threadIdx.x;
    const int bm = blockIdx.x * 64;
    const int bn = blockIdx.y * 64;
    const int tx = t & 15, ty = t >> 4;
    const int lm = t >> 2;
    const int lk = (t & 3) * 4;

    float acc[4][4] = {};

    for (int kc = 0; kc < QD; kc += 16) {
        const float4 yv = *reinterpret_cast<const float4*>(
            &Y[(size_t)(bm + lm) * QD + kc + lk]);
        const float4 wv = *reinterpret_cast<const float4*>(
            &W[(size_t)(bn + lm) * QD + kc + lk]);
        __syncthreads();
        Ys[lk + 0][lm] = yv.x; Ys[lk + 1][lm] = yv.y;
        Ys[lk + 2][lm] = yv.z; Ys[lk + 3][lm] = yv.w;
        Ws[lk + 0][lm] = wv.x; Ws[lk + 1][lm] = wv.y;
        Ws[lk + 2][lm] = wv.z; Ws[lk + 3][lm] = wv.w;
        __syncthreads();
#pragma unroll
        for (int k = 0; k < 16; ++k) {
            const float4 a = *reinterpret_cast<const float4*>(&Ys[k][ty * 4]);
            const float4 bv = *reinterpret_cast<const float4*>(&Ws[k][tx * 4]);
            acc[0][0] += a.x * bv.x; acc[0][1] += a.x * bv.y; acc[0][2] += a.x * bv.z; acc[0][3] += a.x * bv.w;
            acc[1][0] += a.y * bv.x; acc[1][1] += a.y * bv.y; acc[1][2] += a.y * bv.z; acc[1][3] += a.y * bv.w;
            acc[2][0] += a.z * bv.x; acc[2][1] += a.z * bv.y; acc[2][2] += a.z * bv.z; acc[2][3] += a.z * bv.w;
            acc[3][0] += a.w * bv.x; acc[3][1] += a.w * bv.y; acc[3][2] += a.w * bv.z; acc[3][3] += a.w * bv.w;
        }
    }
    const float4 pb4 = *reinterpret_cast<const float4*>(&pbias[bn + tx * 4]);
#pragma unroll
    for (int i = 0; i < 4; ++i) {
        float4 o;
        o.x = acc[i][0] + pb4.x;
        o.y = acc[i][1] + pb4.y;
        o.z = acc[i][2] + pb4.z;
        o.w = acc[i][3] + pb4.w;
        *reinterpret_cast<float4*>(
            &out[(size_t)(bm + ty * 4 + i) * QD + bn + tx * 4]) = o;
    }
}

// ---------------------------------------------------------------------------
// Kernel C: out = LN(lin + y), in-place on d_out (block owns full row).
// ---------------------------------------------------------------------------
__global__ __launch_bounds__(256) void post_ln_kernel(
    float* __restrict__ out, const float* __restrict__ yres,
    const float* __restrict__ lng, const float* __restrict__ lnb)
{
    __shared__ float s_red[8];
    const int r = blockIdx.x;
    const int t = threadIdx.x;
    const int wave = t >> 6, lane = t & 63;
    const int d0 = 2 * t;
    const float2 lv = *reinterpret_cast<const float2*>(&out[(size_t)r * QD + d0]);
    const float2 yv = *reinterpret_cast<const float2*>(&yres[(size_t)r * QD + d0]);
    const float x0 = lv.x + yv.x;
    const float x1 = lv.y + yv.y;
    float sum = red64(x0 + x1);
    float ssq = red64(x0 * x0 + x1 * x1);
    if (lane == 0) { s_red[wave] = sum; s_red[4 + wave] = ssq; }
    __syncthreads();
    sum = s_red[0] + s_red[1] + s_red[2] + s_red[3];
    ssq = s_red[4] + s_red[5] + s_red[6] + s_red[7];
    const float mean = sum * (1.f / QD);
    const float var = ssq * (1.f / QD) - mean * mean;
    const float inv = rsqrtf(var + EPS_LN);
    const float2 gg = *reinterpret_cast<const float2*>(&lng[d0]);
    const float2 bb = *reinterpret_cast<const float2*>(&lnb[d0]);
    float2 o;
    o.x = gg.x * (x0 - mean) * inv + bb.x;
    o.y = gg.y * (x1 - mean) * inv + bb.y;
    *reinterpret_cast<float2*>(&out[(size_t)r * QD + d0]) = o;
}

// ---------------------------------------------------------------------------
extern "C" void kernel_launch(void* const* d_in, const int* in_sizes, int n_in,
                              void* d_out, int out_size, void* d_ws, size_t ws_size,
                              hipStream_t stream) {
    const float* key    = (const float*)d_in[0];   // [B,32,512]
    const float* spa    = (const float*)d_in[1];   // [B,32,64]
    const float* query  = (const float*)d_in[2];   // [B,512]
    const float* av     = (const float*)d_in[3];   // [1088,4]
    const float* postw  = (const float*)d_in[4];   // [512,512]
    const float* postb  = (const float*)d_in[5];   // [512]
    const float* pre_g  = (const float*)d_in[6];
    const float* pre_b  = (const float*)d_in[7];
    const float* post_g = (const float*)d_in[8];
    const float* post_b = (const float*)d_in[9];
    float* out = (float*)d_out;
    float* yws = (float*)d_ws;                     // y (pre-LN'd combined), 8 MB

    const int B = in_sizes[2] / QD;                // 4096

    attn_fuse<<<B, 256, 0, stream>>>(key, spa, query, av, pre_g, pre_b, yws);
    dim3 gridB(B / 64, QD / 64);
    post_gemm<<<gridB, 256, 0, stream>>>(yws, postw, postb, out);
    post_ln_kernel<<<B, 256, 0, stream>>>(out, yws, post_g, post_b);
}

// Round 5
// 127.627 us; speedup vs baseline: 1.2308x; 1.0162x over previous
//
#include <hip/hip_runtime.h>
#include <hip/hip_bf16.h>

#define QD 512
#define SD 64
#define NCTX 32

constexpr float EPS_LN = 1e-6f;
constexpr float SLOPE = 0.01f;

__device__ __forceinline__ float red64(float v) {
#pragma unroll
    for (int m = 32; m; m >>= 1) v += __shfl_xor(v, m, 64);
    return v;
}

__device__ __forceinline__ float b2f(unsigned short u) {
    unsigned int x = ((unsigned int)u) << 16;
    return __builtin_bit_cast(float, x);
}
__device__ __forceinline__ unsigned short f2b(float f) {
    __hip_bfloat16 h = __float2bfloat16(f);
    return __builtin_bit_cast(unsigned short, h);
}

struct __align__(16) US8 { ushort4 a, b; };

// ---------------------------------------------------------------------------
// Kernel A: fused attention + sigmoid + residual + pre-LayerNorm.
// One block per batch element. Staging and logit computation are FUSED:
// wave w loads its own 8 key rows f32 from global (lane owns d=[8l,8l+8)),
// dots them against register-resident atten_vecs (f32 precision), converts
// to bf16 and stores to LDS only for the later weighted-sum phase.
// ---------------------------------------------------------------------------
__global__ __launch_bounds__(256, 4) void attn_fuse(
    const float* __restrict__ key, const float* __restrict__ spa,
    const float* __restrict__ query, const float* __restrict__ av,
    const float* __restrict__ lng, const float* __restrict__ lnb,
    float* __restrict__ yout)
{
    __shared__ __align__(16) unsigned short s_key[NCTX * QD];  // 32 KB bf16
    __shared__ float s_q[QD];                                  // 2 KB
    __shared__ float s_logit[NCTX][4];
    __shared__ float s_w[NCTX];
    __shared__ float s_red[8];

    const int b = blockIdx.x;
    const int t = threadIdx.x;
    const int wave = t >> 6;
    const int lane = t & 63;

    const float* kb = key + (size_t)b * (NCTX * QD);
    const float* qb = query + (size_t)b * QD;
    const float* sb = spa + (size_t)b * (NCTX * SD);
    const float4* av4 = reinterpret_cast<const float4*>(av);   // row d -> 4 heads

    // ---- stage q into LDS (for residual/wsum phase) ----
    if (t < QD / 4) {
        reinterpret_cast<float4*>(s_q)[t] =
            reinterpret_cast<const float4*>(qb)[t];
    }

    // ---- persistent per-lane av slices: lane owns d in [8l, 8l+8) ----
    float4 avk[8];
#pragma unroll
    for (int e = 0; e < 8; ++e) avk[e] = av4[QD + 8 * lane + e];
    const float4 avs = av4[2 * QD + lane];                     // spa row (SD==64)

    // ---- query logit (n-independent), inline from global (L2-hot) ----
    float ql0 = 0.f, ql1 = 0.f, ql2 = 0.f, ql3 = 0.f;
#pragma unroll
    for (int h = 0; h < 2; ++h) {
        const float4 qv = reinterpret_cast<const float4*>(qb)[2 * lane + h];
        const float4 a0 = av4[8 * lane + 4 * h + 0];
        const float4 a1 = av4[8 * lane + 4 * h + 1];
        const float4 a2 = av4[8 * lane + 4 * h + 2];
        const float4 a3 = av4[8 * lane + 4 * h + 3];
        ql0 += qv.x * a0.x + qv.y * a1.x + qv.z * a2.x + qv.w * a3.x;
        ql1 += qv.x * a0.y + qv.y * a1.y + qv.z * a2.y + qv.w * a3.y;
        ql2 += qv.x * a0.z + qv.y * a1.z + qv.z * a2.z + qv.w * a3.z;
        ql3 += qv.x * a0.w + qv.y * a1.w + qv.z * a2.w + qv.w * a3.w;
    }
    ql0 = red64(ql0); ql1 = red64(ql1); ql2 = red64(ql2); ql3 = red64(ql3);

    // ---- fused stage+logit: wave owns rows 8w..8w+7 ----
#pragma unroll
    for (int i = 0; i < 8; ++i) {
        const int n = wave * 8 + i;
        const float* krow = kb + n * QD;
        const float4 k0 = reinterpret_cast<const float4*>(krow)[2 * lane];
        const float4 k1 = reinterpret_cast<const float4*>(krow)[2 * lane + 1];
        const float sv = sb[n * SD + lane];                    // SD==64

        float p0 = sv * avs.x, p1 = sv * avs.y,
              p2 = sv * avs.z, p3 = sv * avs.w;
        p0 += k0.x * avk[0].x + k0.y * avk[1].x + k0.z * avk[2].x + k0.w * avk[3].x
            + k1.x * avk[4].x + k1.y * avk[5].x + k1.z * avk[6].x + k1.w * avk[7].x;
        p1 += k0.x * avk[0].y + k0.y * avk[1].y + k0.z * avk[2].y + k0.w * avk[3].y
            + k1.x * avk[4].y + k1.y * avk[5].y + k1.z * avk[6].y + k1.w * avk[7].y;
        p2 += k0.x * avk[0].z + k0.y * avk[1].z + k0.z * avk[2].z + k0.w * avk[3].z
            + k1.x * avk[4].z + k1.y * avk[5].z + k1.z * avk[6].z + k1.w * avk[7].z;
        p3 += k0.x * avk[0].w + k0.y * avk[1].w + k0.z * avk[2].w + k0.w * avk[3].w
            + k1.x * avk[4].w + k1.y * avk[5].w + k1.z * avk[6].w + k1.w * avk[7].w;

        // bf16 copy for the weighted-sum phase (lane-striped 16B: conflict-free)
        US8 hv;
        hv.a.x = f2b(k0.x); hv.a.y = f2b(k0.y); hv.a.z = f2b(k0.z); hv.a.w = f2b(k0.w);
        hv.b.x = f2b(k1.x); hv.b.y = f2b(k1.y); hv.b.z = f2b(k1.z); hv.b.w = f2b(k1.w);
        *reinterpret_cast<US8*>(&s_key[n * QD + 8 * lane]) = hv;

        p0 = red64(p0); p1 = red64(p1); p2 = red64(p2); p3 = red64(p3);
        if (lane == 0) {
            float l0 = ql0 + p0, l1 = ql1 + p1, l2 = ql2 + p2, l3 = ql3 + p3;
            l0 = l0 > 0.f ? l0 : SLOPE * l0;
            l1 = l1 > 0.f ? l1 : SLOPE * l1;
            l2 = l2 > 0.f ? l2 : SLOPE * l2;
            l3 = l3 > 0.f ? l3 : SLOPE * l3;
            s_logit[n][0] = l0; s_logit[n][1] = l1;
            s_logit[n][2] = l2; s_logit[n][3] = l3;
        }
    }
    __syncthreads();

    // ---- softmax over n per head, w[n] = 0.25 * sum_k attn[n][k] ----
    if (wave == 0) {
        const int n = lane & 31;
        float v0 = s_logit[n][0], v1 = s_logit[n][1],
              v2 = s_logit[n][2], v3 = s_logit[n][3];
        float m0 = v0, m1 = v1, m2 = v2, m3 = v3;
#pragma unroll
        for (int m = 16; m; m >>= 1) {
            m0 = fmaxf(m0, __shfl_xor(m0, m, 32));
            m1 = fmaxf(m1, __shfl_xor(m1, m, 32));
            m2 = fmaxf(m2, __shfl_xor(m2, m, 32));
            m3 = fmaxf(m3, __shfl_xor(m3, m, 32));
        }
        float e0 = __expf(v0 - m0), e1 = __expf(v1 - m1),
              e2 = __expf(v2 - m2), e3 = __expf(v3 - m3);
        float st0 = e0, st1 = e1, st2 = e2, st3 = e3;
#pragma unroll
        for (int m = 16; m; m >>= 1) {
            st0 += __shfl_xor(st0, m, 32);
            st1 += __shfl_xor(st1, m, 32);
            st2 += __shfl_xor(st2, m, 32);
            st3 += __shfl_xor(st3, m, 32);
        }
        const float w = 0.25f * (e0 / st0 + e1 / st1 + e2 / st2 + e3 / st3);
        if (lane < 32) s_w[n] = w;
    }
    __syncthreads();

    // ---- weighted sum over n, sigmoid, +query residual, pre-LN ----
    const int d0 = 2 * t;
    float acc0 = 0.f, acc1 = 0.f;
#pragma unroll
    for (int n = 0; n < NCTX; ++n) {
        const float wn = s_w[n];
        const unsigned int u =
            *reinterpret_cast<const unsigned int*>(&s_key[n * QD + d0]);
        acc0 += wn * b2f((unsigned short)(u & 0xffffu));
        acc1 += wn * b2f((unsigned short)(u >> 16));
    }
    const float x0 = 1.f / (1.f + __expf(-acc0)) + s_q[d0];
    const float x1 = 1.f / (1.f + __expf(-acc1)) + s_q[d0 + 1];

    float sum = red64(x0 + x1);
    float ssq = red64(x0 * x0 + x1 * x1);
    if (lane == 0) { s_red[wave] = sum; s_red[4 + wave] = ssq; }
    __syncthreads();
    sum = s_red[0] + s_red[1] + s_red[2] + s_red[3];
    ssq = s_red[4] + s_red[5] + s_red[6] + s_red[7];
    const float mean = sum * (1.f / QD);
    const float var = ssq * (1.f / QD) - mean * mean;
    const float inv = rsqrtf(var + EPS_LN);
    const float2 gg = *reinterpret_cast<const float2*>(&lng[d0]);
    const float2 bb = *reinterpret_cast<const float2*>(&lnb[d0]);
    float2 o;
    o.x = gg.x * (x0 - mean) * inv + bb.x;
    o.y = gg.y * (x1 - mean) * inv + bb.y;
    *reinterpret_cast<float2*>(&yout[(size_t)b * QD + d0]) = o;
}

// ---------------------------------------------------------------------------
// Kernel B: lin = Y @ W^T + bias.  64x64 tiles, 4x4 micro-tiles, K-chunk 16.
// ---------------------------------------------------------------------------
__global__ __launch_bounds__(256) void post_gemm(
    const float* __restrict__ Y, const float* __restrict__ W,
    const float* __restrict__ pbias, float* __restrict__ out)
{
    __shared__ float Ys[16][68];
    __shared__ float Ws[16][68];
    const int t = threadIdx.x;
    const int bm = blockIdx.x * 64;
    const int bn = blockIdx.y * 64;
    const int tx = t & 15, ty = t >> 4;
    const int lm = t >> 2;
    const int lk = (t & 3) * 4;

    float acc[4][4] = {};

    for (int kc = 0; kc < QD; kc += 16) {
        const float4 yv = *reinterpret_cast<const float4*>(
            &Y[(size_t)(bm + lm) * QD + kc + lk]);
        const float4 wv = *reinterpret_cast<const float4*>(
            &W[(size_t)(bn + lm) * QD + kc + lk]);
        __syncthreads();
        Ys[lk + 0][lm] = yv.x; Ys[lk + 1][lm] = yv.y;
        Ys[lk + 2][lm] = yv.z; Ys[lk + 3][lm] = yv.w;
        Ws[lk + 0][lm] = wv.x; Ws[lk + 1][lm] = wv.y;
        Ws[lk + 2][lm] = wv.z; Ws[lk + 3][lm] = wv.w;
        __syncthreads();
#pragma unroll
        for (int k = 0; k < 16; ++k) {
            const float4 a = *reinterpret_cast<const float4*>(&Ys[k][ty * 4]);
            const float4 bv = *reinterpret_cast<const float4*>(&Ws[k][tx * 4]);
            acc[0][0] += a.x * bv.x; acc[0][1] += a.x * bv.y; acc[0][2] += a.x * bv.z; acc[0][3] += a.x * bv.w;
            acc[1][0] += a.y * bv.x; acc[1][1] += a.y * bv.y; acc[1][2] += a.y * bv.z; acc[1][3] += a.y * bv.w;
            acc[2][0] += a.z * bv.x; acc[2][1] += a.z * bv.y; acc[2][2] += a.z * bv.z; acc[2][3] += a.z * bv.w;
            acc[3][0] += a.w * bv.x; acc[3][1] += a.w * bv.y; acc[3][2] += a.w * bv.z; acc[3][3] += a.w * bv.w;
        }
    }
    const float4 pb4 = *reinterpret_cast<const float4*>(&pbias[bn + tx * 4]);
#pragma unroll
    for (int i = 0; i < 4; ++i) {
        float4 o;
        o.x = acc[i][0] + pb4.x;
        o.y = acc[i][1] + pb4.y;
        o.z = acc[i][2] + pb4.z;
        o.w = acc[i][3] + pb4.w;
        *reinterpret_cast<float4*>(
            &out[(size_t)(bm + ty * 4 + i) * QD + bn + tx * 4]) = o;
    }
}

// ---------------------------------------------------------------------------
// Kernel C: out = LN(lin + y), in-place on d_out (block owns full row).
// ---------------------------------------------------------------------------
__global__ __launch_bounds__(256) void post_ln_kernel(
    float* __restrict__ out, const float* __restrict__ yres,
    const float* __restrict__ lng, const float* __restrict__ lnb)
{
    __shared__ float s_red[8];
    const int r = blockIdx.x;
    const int t = threadIdx.x;
    const int wave = t >> 6, lane = t & 63;
    const int d0 = 2 * t;
    const float2 lv = *reinterpret_cast<const float2*>(&out[(size_t)r * QD + d0]);
    const float2 yv = *reinterpret_cast<const float2*>(&yres[(size_t)r * QD + d0]);
    const float x0 = lv.x + yv.x;
    const float x1 = lv.y + yv.y;
    float sum = red64(x0 + x1);
    float ssq = red64(x0 * x0 + x1 * x1);
    if (lane == 0) { s_red[wave] = sum; s_red[4 + wave] = ssq; }
    __syncthreads();
    sum = s_red[0] + s_red[1] + s_red[2] + s_red[3];
    ssq = s_red[4] + s_red[5] + s_red[6] + s_red[7];
    const float mean = sum * (1.f / QD);
    const float var = ssq * (1.f / QD) - mean * mean;
    const float inv = rsqrtf(var + EPS_LN);
    const float2 gg = *reinterpret_cast<const float2*>(&lng[d0]);
    const float2 bb = *reinterpret_cast<const float2*>(&lnb[d0]);
    float2 o;
    o.x = gg.x * (x0 - mean) * inv + bb.x;
    o.y = gg.y * (x1 - mean) * inv + bb.y;
    *reinterpret_cast<float2*>(&out[(size_t)r * QD + d0]) = o;
}

// ---------------------------------------------------------------------------
extern "C" void kernel_launch(void* const* d_in, const int* in_sizes, int n_in,
                              void* d_out, int out_size, void* d_ws, size_t ws_size,
                              hipStream_t stream) {
    const float* key    = (const float*)d_in[0];   // [B,32,512]
    const float* spa    = (const float*)d_in[1];   // [B,32,64]
    const float* query  = (const float*)d_in[2];   // [B,512]
    const float* av     = (const float*)d_in[3];   // [1088,4]
    const float* postw  = (const float*)d_in[4];   // [512,512]
    const float* postb  = (const float*)d_in[5];   // [512]
    const float* pre_g  = (const float*)d_in[6];
    const float* pre_b  = (const float*)d_in[7];
    const float* post_g = (const float*)d_in[8];
    const float* post_b = (const float*)d_in[9];
    float* out = (float*)d_out;
    float* yws = (float*)d_ws;                     // y (pre-LN'd combined), 8 MB

    const int B = in_sizes[2] / QD;                // 4096

    attn_fuse<<<B, 256, 0, stream>>>(key, spa, query, av, pre_g, pre_b, yws);
    dim3 gridB(B / 64, QD / 64);
    post_gemm<<<gridB, 256, 0, stream>>>(yws, postw, postb, out);
    post_ln_kernel<<<B, 256, 0, stream>>>(out, yws, post_g, post_b);
}

// Round 6
// 109.506 us; speedup vs baseline: 1.4344x; 1.1655x over previous
//
#include <hip/hip_runtime.h>
#include <hip/hip_bf16.h>

#define QD 512
#define SD 64
#define NCTX 32
#define KTOT 576               // QD + SD (MFMA K extent)
#define ROWB 1152              // KTOT * 2 bytes per LDS A-row

constexpr float EPS_LN = 1e-6f;
constexpr float SLOPE = 0.01f;

typedef __attribute__((ext_vector_type(8))) __bf16 bf16x8;
typedef __attribute__((ext_vector_type(4))) float f32x4;

__device__ __forceinline__ float red64(float v) {
#pragma unroll
    for (int m = 32; m; m >>= 1) v += __shfl_xor(v, m, 64);
    return v;
}

__device__ __forceinline__ float b2f(unsigned short u) {
    unsigned int x = ((unsigned int)u) << 16;
    return __builtin_bit_cast(float, x);
}

// XOR-swizzled byte address within the A-tile (row stride 1152 B is a
// multiple of 128 -> unswizzled ds_read_b128 across rows would be a
// 16-way bank conflict; XOR bits 4-6 with row&7 spreads the 16B slots).
__device__ __forceinline__ int swz(int row, int off) {
    return row * ROWB + (off ^ ((row & 7) << 4));
}

__device__ __forceinline__ bf16x8 pack8(float4 a, float4 b) {
    bf16x8 r;
    r[0] = (__bf16)a.x; r[1] = (__bf16)a.y; r[2] = (__bf16)a.z; r[3] = (__bf16)a.w;
    r[4] = (__bf16)b.x; r[5] = (__bf16)b.y; r[6] = (__bf16)b.z; r[7] = (__bf16)b.w;
    return r;
}

// ---------------------------------------------------------------------------
// Kernel A: fused attention + sigmoid + residual + pre-LayerNorm.
// One block per batch element. Logits computed with MFMA:
//   A (LDS, bf16, swizzled) = [32 rows n][576 = key(512) | spa(64)]
//   B (LDS, bf16)           = av rows 512..1087 -> [4 cols][576 k] (cols 4..15 = 0)
//   logit[n][k] = ql[k] + (A.B)[n][k], ql = query . av[0:512] (wave 3, red64)
// This removes ~290 VALU FMAs and 32 serial 6-step shuffle reductions/wave.
// ---------------------------------------------------------------------------
__global__ __launch_bounds__(256, 3) void attn_fuse(
    const float* __restrict__ key, const float* __restrict__ spa,
    const float* __restrict__ query, const float* __restrict__ av,
    const float* __restrict__ lng, const float* __restrict__ lnb,
    float* __restrict__ yout)
{
    __shared__ __align__(16) unsigned char s_A[NCTX * ROWB];  // 36864 B
    __shared__ __align__(16) unsigned char s_B[4 * ROWB];     // 4608 B
    __shared__ float s_logit[NCTX][4];
    __shared__ float s_w[NCTX];
    __shared__ float s_red[8];
    __shared__ float s_ql[4];

    const int b = blockIdx.x;
    const int t = threadIdx.x;
    const int wave = t >> 6;
    const int lane = t & 63;

    const float* kb = key + (size_t)b * (NCTX * QD);
    const float* qb = query + (size_t)b * QD;
    const float* sb = spa + (size_t)b * (NCTX * SD);
    const float4* av4 = reinterpret_cast<const float4*>(av);   // row d -> 4 heads

    // ================= phase 1: staging (all loads issued first) ==========
    // key: wave w owns rows 8w..8w+7, lane owns cols [8l, 8l+8)
    float4 kreg[16];
#pragma unroll
    for (int i = 0; i < 8; ++i) {
        const float* krow = kb + (8 * wave + i) * QD;
        kreg[2 * i]     = reinterpret_cast<const float4*>(krow)[2 * lane];
        kreg[2 * i + 1] = reinterpret_cast<const float4*>(krow)[2 * lane + 1];
    }
    // spa: wave w rows 8w..8w+7; lane -> (row i2 = l>>3, col-group j = l&7)
    const int i2 = lane >> 3, j8 = lane & 7;
    const float* srow = sb + (8 * wave + i2) * SD + 8 * j8;
    const float4 sreg0 = reinterpret_cast<const float4*>(srow)[0];
    const float4 sreg1 = reinterpret_cast<const float4*>(srow)[1];
    // B-matrix: wave w stages av column w (heads 0..3), 9 k's per lane
    float avreg[9];
#pragma unroll
    for (int r = 0; r < 9; ++r)
        avreg[r] = av[(size_t)(512 + lane * 9 + r) * 4 + wave];

    // writes (bf16, swizzled)
#pragma unroll
    for (int i = 0; i < 8; ++i) {
        const int n = 8 * wave + i;
        *reinterpret_cast<bf16x8*>(&s_A[swz(n, 16 * lane)]) =
            pack8(kreg[2 * i], kreg[2 * i + 1]);
    }
    *reinterpret_cast<bf16x8*>(&s_A[swz(8 * wave + i2, 1024 + 16 * j8)]) =
        pack8(sreg0, sreg1);
#pragma unroll
    for (int r = 0; r < 9; ++r) {
        const int k = lane * 9 + r;
        *reinterpret_cast<__bf16*>(&s_B[wave * ROWB + ((2 * k) ^ (wave << 4))]) =
            (__bf16)avreg[r];
    }

    // wave 3: query logit ql[k] = sum_d q[d]*av[d][k]  (n-independent)
    if (wave == 3) {
        const float4* q4 = reinterpret_cast<const float4*>(qb);
        float s0 = 0.f, s1 = 0.f, s2 = 0.f, s3 = 0.f;
#pragma unroll
        for (int h = 0; h < 2; ++h) {
            const float4 qv = q4[2 * lane + h];
            const float4 a0 = av4[8 * lane + 4 * h + 0];
            const float4 a1 = av4[8 * lane + 4 * h + 1];
            const float4 a2 = av4[8 * lane + 4 * h + 2];
            const float4 a3 = av4[8 * lane + 4 * h + 3];
            s0 += qv.x * a0.x + qv.y * a1.x + qv.z * a2.x + qv.w * a3.x;
            s1 += qv.x * a0.y + qv.y * a1.y + qv.z * a2.y + qv.w * a3.y;
            s2 += qv.x * a0.z + qv.y * a1.z + qv.z * a2.z + qv.w * a3.z;
            s3 += qv.x * a0.w + qv.y * a1.w + qv.z * a2.w + qv.w * a3.w;
        }
        s0 = red64(s0); s1 = red64(s1); s2 = red64(s2); s3 = red64(s3);
        if (lane == 0) { s_ql[0] = s0; s_ql[1] = s1; s_ql[2] = s2; s_ql[3] = s3; }
    }
    __syncthreads();

    // ================= phase 2: MFMA logits (waves 0,1) ===================
    if (wave < 2) {
        const int colB = lane & 15;
        const int kgrp = (lane >> 4) * 16;       // byte offset of this lane's k-octet
        const int arow = 16 * wave + (lane & 15);
        f32x4 acc = {0.f, 0.f, 0.f, 0.f};
        bf16x8 bz;
#pragma unroll
        for (int e = 0; e < 8; ++e) bz[e] = (__bf16)0.0f;
#pragma unroll
        for (int ks = 0; ks < 18; ++ks) {
            const int koff = ks * 64 + kgrp;     // bytes within row
            const bf16x8 af =
                *reinterpret_cast<const bf16x8*>(&s_A[swz(arow, koff)]);
            bf16x8 bf = bz;
            if (colB < 4)
                bf = *reinterpret_cast<const bf16x8*>(
                    &s_B[colB * ROWB + (koff ^ (colB << 4))]);
            acc = __builtin_amdgcn_mfma_f32_16x16x32_bf16(af, bf, acc, 0, 0, 0);
        }
        if (colB < 4) {
            const float qlk = s_ql[colB];
#pragma unroll
            for (int r = 0; r < 4; ++r) {
                const int row = 16 * wave + (lane >> 4) * 4 + r;  // C/D: m89 layout
                float v = acc[r] + qlk;
                v = v > 0.f ? v : SLOPE * v;
                s_logit[row][colB] = v;
            }
        }
    }
    __syncthreads();

    // ================= phase 3: softmax over n per head ===================
    if (wave == 0) {
        const int n = lane & 31;
        float v0 = s_logit[n][0], v1 = s_logit[n][1],
              v2 = s_logit[n][2], v3 = s_logit[n][3];
        float m0 = v0, m1 = v1, m2 = v2, m3 = v3;
#pragma unroll
        for (int m = 16; m; m >>= 1) {
            m0 = fmaxf(m0, __shfl_xor(m0, m, 32));
            m1 = fmaxf(m1, __shfl_xor(m1, m, 32));
            m2 = fmaxf(m2, __shfl_xor(m2, m, 32));
            m3 = fmaxf(m3, __shfl_xor(m3, m, 32));
        }
        float e0 = __expf(v0 - m0), e1 = __expf(v1 - m1),
              e2 = __expf(v2 - m2), e3 = __expf(v3 - m3);
        float st0 = e0, st1 = e1, st2 = e2, st3 = e3;
#pragma unroll
        for (int m = 16; m; m >>= 1) {
            st0 += __shfl_xor(st0, m, 32);
            st1 += __shfl_xor(st1, m, 32);
            st2 += __shfl_xor(st2, m, 32);
            st3 += __shfl_xor(st3, m, 32);
        }
        const float w = 0.25f * (e0 / st0 + e1 / st1 + e2 / st2 + e3 / st3);
        if (lane < 32) s_w[n] = w;
    }
    __syncthreads();

    // ======= phase 4: weighted sum, sigmoid, +query residual, pre-LN ======
    const int d0 = 2 * t;
    float acc0 = 0.f, acc1 = 0.f;
#pragma unroll
    for (int n = 0; n < NCTX; ++n) {
        const float wn = s_w[n];
        const unsigned int u =
            *reinterpret_cast<const unsigned int*>(&s_A[swz(n, 4 * t)]);
        acc0 += wn * b2f((unsigned short)(u & 0xffffu));
        acc1 += wn * b2f((unsigned short)(u >> 16));
    }
    const float2 qv = *reinterpret_cast<const float2*>(&qb[d0]);
    const float x0 = 1.f / (1.f + __expf(-acc0)) + qv.x;
    const float x1 = 1.f / (1.f + __expf(-acc1)) + qv.y;

    float sum = red64(x0 + x1);
    float ssq = red64(x0 * x0 + x1 * x1);
    if (lane == 0) { s_red[wave] = sum; s_red[4 + wave] = ssq; }
    __syncthreads();
    sum = s_red[0] + s_red[1] + s_red[2] + s_red[3];
    ssq = s_red[4] + s_red[5] + s_red[6] + s_red[7];
    const float mean = sum * (1.f / QD);
    const float var = ssq * (1.f / QD) - mean * mean;
    const float inv = rsqrtf(var + EPS_LN);
    const float2 gg = *reinterpret_cast<const float2*>(&lng[d0]);
    const float2 bb = *reinterpret_cast<const float2*>(&lnb[d0]);
    float2 o;
    o.x = gg.x * (x0 - mean) * inv + bb.x;
    o.y = gg.y * (x1 - mean) * inv + bb.y;
    *reinterpret_cast<float2*>(&yout[(size_t)b * QD + d0]) = o;
}

// ---------------------------------------------------------------------------
// Kernel B: lin = Y @ W^T + bias.  64x64 tiles, 4x4 micro-tiles, K-chunk 16.
// ---------------------------------------------------------------------------
__global__ __launch_bounds__(256) void post_gemm(
    const float* __restrict__ Y, const float* __restrict__ W,
    const float* __restrict__ pbias, float* __restrict__ out)
{
    __shared__ float Ys[16][68];
    __shared__ float Ws[16][68];
    const int t = threadIdx.x;
    const int bm = blockIdx.x * 64;
    const int bn = blockIdx.y * 64;
    const int tx = t & 15, ty = t >> 4;
    const int lm = t >> 2;
    const int lk = (t & 3) * 4;

    float acc[4][4] = {};

    for (int kc = 0; kc < QD; kc += 16) {
        const float4 yv = *reinterpret_cast<const float4*>(
            &Y[(size_t)(bm + lm) * QD + kc + lk]);
        const float4 wv = *reinterpret_cast<const float4*>(
            &W[(size_t)(bn + lm) * QD + kc + lk]);
        __syncthreads();
        Ys[lk + 0][lm] = yv.x; Ys[lk + 1][lm] = yv.y;
        Ys[lk + 2][lm] = yv.z; Ys[lk + 3][lm] = yv.w;
        Ws[lk + 0][lm] = wv.x; Ws[lk + 1][lm] = wv.y;
        Ws[lk + 2][lm] = wv.z; Ws[lk + 3][lm] = wv.w;
        __syncthreads();
#pragma unroll
        for (int k = 0; k < 16; ++k) {
            const float4 a = *reinterpret_cast<const float4*>(&Ys[k][ty * 4]);
            const float4 bv = *reinterpret_cast<const float4*>(&Ws[k][tx * 4]);
            acc[0][0] += a.x * bv.x; acc[0][1] += a.x * bv.y; acc[0][2] += a.x * bv.z; acc[0][3] += a.x * bv.w;
            acc[1][0] += a.y * bv.x; acc[1][1] += a.y * bv.y; acc[1][2] += a.y * bv.z; acc[1][3] += a.y * bv.w;
            acc[2][0] += a.z * bv.x; acc[2][1] += a.z * bv.y; acc[2][2] += a.z * bv.z; acc[2][3] += a.z * bv.w;
            acc[3][0] += a.w * bv.x; acc[3][1] += a.w * bv.y; acc[3][2] += a.w * bv.z; acc[3][3] += a.w * bv.w;
        }
    }
    const float4 pb4 = *reinterpret_cast<const float4*>(&pbias[bn + tx * 4]);
#pragma unroll
    for (int i = 0; i < 4; ++i) {
        float4 o;
        o.x = acc[i][0] + pb4.x;
        o.y = acc[i][1] + pb4.y;
        o.z = acc[i][2] + pb4.z;
        o.w = acc[i][3] + pb4.w;
        *reinterpret_cast<float4*>(
            &out[(size_t)(bm + ty * 4 + i) * QD + bn + tx * 4]) = o;
    }
}

// ---------------------------------------------------------------------------
// Kernel C: out = LN(lin + y), in-place on d_out (block owns full row).
// ---------------------------------------------------------------------------
__global__ __launch_bounds__(256) void post_ln_kernel(
    float* __restrict__ out, const float* __restrict__ yres,
    const float* __restrict__ lng, const float* __restrict__ lnb)
{
    __shared__ float s_red[8];
    const int r = blockIdx.x;
    const int t = threadIdx.x;
    const int wave = t >> 6, lane = t & 63;
    const int d0 = 2 * t;
    const float2 lv = *reinterpret_cast<const float2*>(&out[(size_t)r * QD + d0]);
    const float2 yv = *reinterpret_cast<const float2*>(&yres[(size_t)r * QD + d0]);
    const float x0 = lv.x + yv.x;
    const float x1 = lv.y + yv.y;
    float sum = red64(x0 + x1);
    float ssq = red64(x0 * x0 + x1 * x1);
    if (lane == 0) { s_red[wave] = sum; s_red[4 + wave] = ssq; }
    __syncthreads();
    sum = s_red[0] + s_red[1] + s_red[2] + s_red[3];
    ssq = s_red[4] + s_red[5] + s_red[6] + s_red[7];
    const float mean = sum * (1.f / QD);
    const float var = ssq * (1.f / QD) - mean * mean;
    const float inv = rsqrtf(var + EPS_LN);
    const float2 gg = *reinterpret_cast<const float2*>(&lng[d0]);
    const float2 bb = *reinterpret_cast<const float2*>(&lnb[d0]);
    float2 o;
    o.x = gg.x * (x0 - mean) * inv + bb.x;
    o.y = gg.y * (x1 - mean) * inv + bb.y;
    *reinterpret_cast<float2*>(&out[(size_t)r * QD + d0]) = o;
}

// ---------------------------------------------------------------------------
extern "C" void kernel_launch(void* const* d_in, const int* in_sizes, int n_in,
                              void* d_out, int out_size, void* d_ws, size_t ws_size,
                              hipStream_t stream) {
    const float* key    = (const float*)d_in[0];   // [B,32,512]
    const float* spa    = (const float*)d_in[1];   // [B,32,64]
    const float* query  = (const float*)d_in[2];   // [B,512]
    const float* av     = (const float*)d_in[3];   // [1088,4]
    const float* postw  = (const float*)d_in[4];   // [512,512]
    const float* postb  = (const float*)d_in[5];   // [512]
    const float* pre_g  = (const float*)d_in[6];
    const float* pre_b  = (const float*)d_in[7];
    const float* post_g = (const float*)d_in[8];
    const float* post_b = (const float*)d_in[9];
    float* out = (float*)d_out;
    float* yws = (float*)d_ws;                     // y (pre-LN'd combined), 8 MB

    const int B = in_sizes[2] / QD;                // 4096

    attn_fuse<<<B, 256, 0, stream>>>(key, spa, query, av, pre_g, pre_b, yws);
    dim3 gridB(B / 64, QD / 64);
    post_gemm<<<gridB, 256, 0, stream>>>(yws, postw, postb, out);
    post_ln_kernel<<<B, 256, 0, stream>>>(out, yws, post_g, post_b);
}

// Round 7
// 85.366 us; speedup vs baseline: 1.8401x; 1.2828x over previous
//
#include <hip/hip_runtime.h>
#include <hip/hip_bf16.h>

#define QD 512
#define SD 64
#define NCTX 32
#define KTOT 576               // QD + SD (MFMA K extent)
#define ROWB 1152              // KTOT * 2 bytes per LDS A-row

constexpr float EPS_LN = 1e-6f;
constexpr float SLOPE = 0.01f;

typedef __attribute__((ext_vector_type(8))) __bf16 bf16x8;
typedef __attribute__((ext_vector_type(4))) float f32x4;

__device__ __forceinline__ float red64(float v) {
#pragma unroll
    for (int m = 32; m; m >>= 1) v += __shfl_xor(v, m, 64);
    return v;
}

__device__ __forceinline__ float b2f(unsigned short u) {
    unsigned int x = ((unsigned int)u) << 16;
    return __builtin_bit_cast(float, x);
}

// XOR-swizzled byte address within the A-tile (row stride 1152 B is a
// multiple of 128 -> unswizzled ds_read_b128 across rows would be a
// 16-way bank conflict; XOR bits 4-6 with row&7 spreads the 16B slots).
__device__ __forceinline__ int swz(int row, int off) {
    return row * ROWB + (off ^ ((row & 7) << 4));
}

__device__ __forceinline__ bf16x8 pack8(float4 a, float4 b) {
    bf16x8 r;
    r[0] = (__bf16)a.x; r[1] = (__bf16)a.y; r[2] = (__bf16)a.z; r[3] = (__bf16)a.w;
    r[4] = (__bf16)b.x; r[5] = (__bf16)b.y; r[6] = (__bf16)b.z; r[7] = (__bf16)b.w;
    return r;
}

// ---------------------------------------------------------------------------
// Kernel A: fused attention + sigmoid + residual + pre-LayerNorm.
// One block per batch element. Logits computed with MFMA:
//   A (LDS, bf16, swizzled) = [32 rows n][576 = key(512) | spa(64)]
//   B (LDS, bf16)           = av rows 512..1087 -> [4 cols][576 k] (cols 4..15 = 0)
//   logit[n][k] = ql[k] + (A.B)[n][k], ql = query . av[0:512] (wave 3, red64)
// ---------------------------------------------------------------------------
__global__ __launch_bounds__(256, 3) void attn_fuse(
    const float* __restrict__ key, const float* __restrict__ spa,
    const float* __restrict__ query, const float* __restrict__ av,
    const float* __restrict__ lng, const float* __restrict__ lnb,
    float* __restrict__ yout)
{
    __shared__ __align__(16) unsigned char s_A[NCTX * ROWB];  // 36864 B
    __shared__ __align__(16) unsigned char s_B[4 * ROWB];     // 4608 B
    __shared__ float s_logit[NCTX][4];
    __shared__ float s_w[NCTX];
    __shared__ float s_red[8];
    __shared__ float s_ql[4];

    const int b = blockIdx.x;
    const int t = threadIdx.x;
    const int wave = t >> 6;
    const int lane = t & 63;

    const float* kb = key + (size_t)b * (NCTX * QD);
    const float* qb = query + (size_t)b * QD;
    const float* sb = spa + (size_t)b * (NCTX * SD);
    const float4* av4 = reinterpret_cast<const float4*>(av);   // row d -> 4 heads

    // ================= phase 1: staging (all loads issued first) ==========
    float4 kreg[16];
#pragma unroll
    for (int i = 0; i < 8; ++i) {
        const float* krow = kb + (8 * wave + i) * QD;
        kreg[2 * i]     = reinterpret_cast<const float4*>(krow)[2 * lane];
        kreg[2 * i + 1] = reinterpret_cast<const float4*>(krow)[2 * lane + 1];
    }
    const int i2 = lane >> 3, j8 = lane & 7;
    const float* srow = sb + (8 * wave + i2) * SD + 8 * j8;
    const float4 sreg0 = reinterpret_cast<const float4*>(srow)[0];
    const float4 sreg1 = reinterpret_cast<const float4*>(srow)[1];
    float avreg[9];
#pragma unroll
    for (int r = 0; r < 9; ++r)
        avreg[r] = av[(size_t)(512 + lane * 9 + r) * 4 + wave];

#pragma unroll
    for (int i = 0; i < 8; ++i) {
        const int n = 8 * wave + i;
        *reinterpret_cast<bf16x8*>(&s_A[swz(n, 16 * lane)]) =
            pack8(kreg[2 * i], kreg[2 * i + 1]);
    }
    *reinterpret_cast<bf16x8*>(&s_A[swz(8 * wave + i2, 1024 + 16 * j8)]) =
        pack8(sreg0, sreg1);
#pragma unroll
    for (int r = 0; r < 9; ++r) {
        const int k = lane * 9 + r;
        *reinterpret_cast<__bf16*>(&s_B[wave * ROWB + ((2 * k) ^ (wave << 4))]) =
            (__bf16)avreg[r];
    }

    // wave 3: query logit ql[k] = sum_d q[d]*av[d][k]  (n-independent)
    if (wave == 3) {
        const float4* q4 = reinterpret_cast<const float4*>(qb);
        float s0 = 0.f, s1 = 0.f, s2 = 0.f, s3 = 0.f;
#pragma unroll
        for (int h = 0; h < 2; ++h) {
            const float4 qv = q4[2 * lane + h];
            const float4 a0 = av4[8 * lane + 4 * h + 0];
            const float4 a1 = av4[8 * lane + 4 * h + 1];
            const float4 a2 = av4[8 * lane + 4 * h + 2];
            const float4 a3 = av4[8 * lane + 4 * h + 3];
            s0 += qv.x * a0.x + qv.y * a1.x + qv.z * a2.x + qv.w * a3.x;
            s1 += qv.x * a0.y + qv.y * a1.y + qv.z * a2.y + qv.w * a3.y;
            s2 += qv.x * a0.z + qv.y * a1.z + qv.z * a2.z + qv.w * a3.z;
            s3 += qv.x * a0.w + qv.y * a1.w + qv.z * a2.w + qv.w * a3.w;
        }
        s0 = red64(s0); s1 = red64(s1); s2 = red64(s2); s3 = red64(s3);
        if (lane == 0) { s_ql[0] = s0; s_ql[1] = s1; s_ql[2] = s2; s_ql[3] = s3; }
    }
    __syncthreads();

    // ================= phase 2: MFMA logits (waves 0,1) ===================
    if (wave < 2) {
        const int colB = lane & 15;
        const int kgrp = (lane >> 4) * 16;
        const int arow = 16 * wave + (lane & 15);
        f32x4 acc = {0.f, 0.f, 0.f, 0.f};
        bf16x8 bz;
#pragma unroll
        for (int e = 0; e < 8; ++e) bz[e] = (__bf16)0.0f;
#pragma unroll
        for (int ks = 0; ks < 18; ++ks) {
            const int koff = ks * 64 + kgrp;
            const bf16x8 af =
                *reinterpret_cast<const bf16x8*>(&s_A[swz(arow, koff)]);
            bf16x8 bf = bz;
            if (colB < 4)
                bf = *reinterpret_cast<const bf16x8*>(
                    &s_B[colB * ROWB + (koff ^ (colB << 4))]);
            acc = __builtin_amdgcn_mfma_f32_16x16x32_bf16(af, bf, acc, 0, 0, 0);
        }
        if (colB < 4) {
            const float qlk = s_ql[colB];
#pragma unroll
            for (int r = 0; r < 4; ++r) {
                const int row = 16 * wave + (lane >> 4) * 4 + r;  // C/D: m89 layout
                float v = acc[r] + qlk;
                v = v > 0.f ? v : SLOPE * v;
                s_logit[row][colB] = v;
            }
        }
    }
    __syncthreads();

    // ================= phase 3: softmax over n per head ===================
    if (wave == 0) {
        const int n = lane & 31;
        float v0 = s_logit[n][0], v1 = s_logit[n][1],
              v2 = s_logit[n][2], v3 = s_logit[n][3];
        float m0 = v0, m1 = v1, m2 = v2, m3 = v3;
#pragma unroll
        for (int m = 16; m; m >>= 1) {
            m0 = fmaxf(m0, __shfl_xor(m0, m, 32));
            m1 = fmaxf(m1, __shfl_xor(m1, m, 32));
            m2 = fmaxf(m2, __shfl_xor(m2, m, 32));
            m3 = fmaxf(m3, __shfl_xor(m3, m, 32));
        }
        float e0 = __expf(v0 - m0), e1 = __expf(v1 - m1),
              e2 = __expf(v2 - m2), e3 = __expf(v3 - m3);
        float st0 = e0, st1 = e1, st2 = e2, st3 = e3;
#pragma unroll
        for (int m = 16; m; m >>= 1) {
            st0 += __shfl_xor(st0, m, 32);
            st1 += __shfl_xor(st1, m, 32);
            st2 += __shfl_xor(st2, m, 32);
            st3 += __shfl_xor(st3, m, 32);
        }
        const float w = 0.25f * (e0 / st0 + e1 / st1 + e2 / st2 + e3 / st3);
        if (lane < 32) s_w[n] = w;
    }
    __syncthreads();

    // ======= phase 4: weighted sum, sigmoid, +query residual, pre-LN ======
    const int d0 = 2 * t;
    float acc0 = 0.f, acc1 = 0.f;
#pragma unroll
    for (int n = 0; n < NCTX; ++n) {
        const float wn = s_w[n];
        const unsigned int u =
            *reinterpret_cast<const unsigned int*>(&s_A[swz(n, 4 * t)]);
        acc0 += wn * b2f((unsigned short)(u & 0xffffu));
        acc1 += wn * b2f((unsigned short)(u >> 16));
    }
    const float2 qv = *reinterpret_cast<const float2*>(&qb[d0]);
    const float x0 = 1.f / (1.f + __expf(-acc0)) + qv.x;
    const float x1 = 1.f / (1.f + __expf(-acc1)) + qv.y;

    float sum = red64(x0 + x1);
    float ssq = red64(x0 * x0 + x1 * x1);
    if (lane == 0) { s_red[wave] = sum; s_red[4 + wave] = ssq; }
    __syncthreads();
    sum = s_red[0] + s_red[1] + s_red[2] + s_red[3];
    ssq = s_red[4] + s_red[5] + s_red[6] + s_red[7];
    const float mean = sum * (1.f / QD);
    const float var = ssq * (1.f / QD) - mean * mean;
    const float inv = rsqrtf(var + EPS_LN);
    const float2 gg = *reinterpret_cast<const float2*>(&lng[d0]);
    const float2 bb = *reinterpret_cast<const float2*>(&lnb[d0]);
    float2 o;
    o.x = gg.x * (x0 - mean) * inv + bb.x;
    o.y = gg.y * (x1 - mean) * inv + bb.y;
    *reinterpret_cast<float2*>(&yout[(size_t)b * QD + d0]) = o;
}

// ---------------------------------------------------------------------------
// Kernel B: lin = Y @ W^T + bias, bf16 MFMA.  64x64 tile, BK=64, 4 waves.
// Wave w owns rows [16w,16w+16) x 64 cols (4 subtiles, acc = 4 x f32x4).
// Both Y and W are row-major K-contiguous ("B^T input"): fragments are
// straight ds_read_b128 of 8 consecutive k. Tiles XOR-swizzled (T2):
// row stride 128 B, byte ^= (row&7)<<4 -> residual 2-way aliasing (free).
// ---------------------------------------------------------------------------
__device__ __forceinline__ int swzB(int row, int off) {
    return row * 128 + (off ^ ((row & 7) << 4));
}

__global__ __launch_bounds__(256) void post_gemm(
    const float* __restrict__ Y, const float* __restrict__ W,
    const float* __restrict__ pbias, float* __restrict__ out)
{
    __shared__ __align__(16) unsigned char Ys[64 * 128];  // 8 KB bf16 [64][64]
    __shared__ __align__(16) unsigned char Ws[64 * 128];  // 8 KB
    const int t = threadIdx.x;
    const int wave = t >> 6, lane = t & 63;
    const int bm = blockIdx.x * 64;
    const int bn = blockIdx.y * 64;

    const int lr = t >> 2;          // 0..63: tile row this thread stages
    const int lq = (t & 3) * 16;    // k offset (floats) within BK=64

    f32x4 acc[4] = {{0.f,0.f,0.f,0.f},{0.f,0.f,0.f,0.f},
                    {0.f,0.f,0.f,0.f},{0.f,0.f,0.f,0.f}};

    for (int kc = 0; kc < QD; kc += 64) {
        float4 ya[4], wa[4];
        const float* yrow = Y + (size_t)(bm + lr) * QD + kc + lq;
        const float* wrow = W + (size_t)(bn + lr) * QD + kc + lq;
#pragma unroll
        for (int j = 0; j < 4; ++j) {
            ya[j] = reinterpret_cast<const float4*>(yrow)[j];
            wa[j] = reinterpret_cast<const float4*>(wrow)[j];
        }
        __syncthreads();   // previous iteration's reads complete
        const int base = lq * 2;   // byte offset of first bf16
        *reinterpret_cast<bf16x8*>(&Ys[swzB(lr, base)])      = pack8(ya[0], ya[1]);
        *reinterpret_cast<bf16x8*>(&Ys[swzB(lr, base + 16)]) = pack8(ya[2], ya[3]);
        *reinterpret_cast<bf16x8*>(&Ws[swzB(lr, base)])      = pack8(wa[0], wa[1]);
        *reinterpret_cast<bf16x8*>(&Ws[swzB(lr, base + 16)]) = pack8(wa[2], wa[3]);
        __syncthreads();
#pragma unroll
        for (int ks = 0; ks < 2; ++ks) {
            const int ko = ks * 64 + (lane >> 4) * 16;  // byte offset in row
            const bf16x8 af = *reinterpret_cast<const bf16x8*>(
                &Ys[swzB(16 * wave + (lane & 15), ko)]);
#pragma unroll
            for (int c = 0; c < 4; ++c) {
                const bf16x8 bf = *reinterpret_cast<const bf16x8*>(
                    &Ws[swzB(16 * c + (lane & 15), ko)]);
                acc[c] = __builtin_amdgcn_mfma_f32_16x16x32_bf16(af, bf, acc[c],
                                                                 0, 0, 0);
            }
        }
    }
    // epilogue: C/D layout (m89): n = lane&15, m = (lane>>4)*4 + r
    const int m0 = bm + 16 * wave + (lane >> 4) * 4;
#pragma unroll
    for (int c = 0; c < 4; ++c) {
        const int n = bn + 16 * c + (lane & 15);
        const float pb = pbias[n];
#pragma unroll
        for (int r = 0; r < 4; ++r) {
            out[(size_t)(m0 + r) * QD + n] = acc[c][r] + pb;
        }
    }
}

// ---------------------------------------------------------------------------
// Kernel C: out = LN(lin + y), in-place on d_out (block owns full row).
// ---------------------------------------------------------------------------
__global__ __launch_bounds__(256) void post_ln_kernel(
    float* __restrict__ out, const float* __restrict__ yres,
    const float* __restrict__ lng, const float* __restrict__ lnb)
{
    __shared__ float s_red[8];
    const int r = blockIdx.x;
    const int t = threadIdx.x;
    const int wave = t >> 6, lane = t & 63;
    const int d0 = 2 * t;
    const float2 lv = *reinterpret_cast<const float2*>(&out[(size_t)r * QD + d0]);
    const float2 yv = *reinterpret_cast<const float2*>(&yres[(size_t)r * QD + d0]);
    const float x0 = lv.x + yv.x;
    const float x1 = lv.y + yv.y;
    float sum = red64(x0 + x1);
    float ssq = red64(x0 * x0 + x1 * x1);
    if (lane == 0) { s_red[wave] = sum; s_red[4 + wave] = ssq; }
    __syncthreads();
    sum = s_red[0] + s_red[1] + s_red[2] + s_red[3];
    ssq = s_red[4] + s_red[5] + s_red[6] + s_red[7];
    const float mean = sum * (1.f / QD);
    const float var = ssq * (1.f / QD) - mean * mean;
    const float inv = rsqrtf(var + EPS_LN);
    const float2 gg = *reinterpret_cast<const float2*>(&lng[d0]);
    const float2 bb = *reinterpret_cast<const float2*>(&lnb[d0]);
    float2 o;
    o.x = gg.x * (x0 - mean) * inv + bb.x;
    o.y = gg.y * (x1 - mean) * inv + bb.y;
    *reinterpret_cast<float2*>(&out[(size_t)r * QD + d0]) = o;
}

// ---------------------------------------------------------------------------
extern "C" void kernel_launch(void* const* d_in, const int* in_sizes, int n_in,
                              void* d_out, int out_size, void* d_ws, size_t ws_size,
                              hipStream_t stream) {
    const float* key    = (const float*)d_in[0];   // [B,32,512]
    const float* spa    = (const float*)d_in[1];   // [B,32,64]
    const float* query  = (const float*)d_in[2];   // [B,512]
    const float* av     = (const float*)d_in[3];   // [1088,4]
    const float* postw  = (const float*)d_in[4];   // [512,512]
    const float* postb  = (const float*)d_in[5];   // [512]
    const float* pre_g  = (const float*)d_in[6];
    const float* pre_b  = (const float*)d_in[7];
    const float* post_g = (const float*)d_in[8];
    const float* post_b = (const float*)d_in[9];
    float* out = (float*)d_out;
    float* yws = (float*)d_ws;                     // y (pre-LN'd combined), 8 MB

    const int B = in_sizes[2] / QD;                // 4096

    attn_fuse<<<B, 256, 0, stream>>>(key, spa, query, av, pre_g, pre_b, yws);
    dim3 gridB(B / 64, QD / 64);
    post_gemm<<<gridB, 256, 0, stream>>>(yws, postw, postb, out);
    post_ln_kernel<<<B, 256, 0, stream>>>(out, yws, post_g, post_b);
}